// Round 6
// baseline (179.424 us; speedup 1.0000x reference)
//
#include <hip/hip_runtime.h>

// out = x + softmax((x@Wq) @ (rs@Wk)^T) @ (rs@Wv)
// B=4 T=8 N=2048 C=D=128 M=2048. fp32 in/out, fp16 MFMA compute (f32 accum).
// R5b: K A-fragments loaded straight from L2 (global->reg, off the DS pipe);
//     V via LDS dbuf DMA; P packed-b32 round-trip; defer-max; exp2 w/ log2e
//     folded into Q; XCD-chunked block mapping (1 batch per XCD pair).
//     (fix: cvt_pkrtz return type -> bit_cast to u32)

#define Bn 4
#define Tn 8
#define Nn 2048
#define Cn 128
#define Mn 2048
#define NTILES 32        // Mn/64
#define QROWS 128
#define NQT (Nn / QROWS) // 16

typedef __attribute__((ext_vector_type(4))) float f32x4;
typedef __attribute__((ext_vector_type(8))) _Float16 f16x8;
typedef __attribute__((address_space(3))) unsigned char lds_uc;
typedef const __attribute__((address_space(1))) unsigned char glb_uc;

__device__ __forceinline__ unsigned short f2h(float f) {
  _Float16 h = (_Float16)f;
  return __builtin_bit_cast(unsigned short, h);
}
// Swizzled LDS read of 8 f16 (16B). byte ^= (row&7)<<4 (bank-conflict fix).
__device__ __forceinline__ f16x8 lds_read8(const unsigned char* base, int row,
                                           int rowBytes, int colByte) {
  int byte = row * rowBytes + (colByte ^ ((row & 7) << 4));
  return *(const f16x8*)(base + byte);
}
__device__ __forceinline__ void gld16(const void* g, void* l) {
  __builtin_amdgcn_global_load_lds((glb_uc*)g, (lds_uc*)l, 16, 0, 0);
}

// ---------------------------------------------------------------------------
// Kernel A: per (b,kt): K tile [64 m][128 d] f16 LINEAR row-major (read from
// global as A-frags by attn), V^T tile [128 d][64 m] f16 PRE-SWIZZLED (staged
// to LDS by DMA). k_ws/vt_ws: [B][NTILES][8192] f16.
// grid: B*NTILES = 128 blocks, 256 threads. LDS 48KB.
// ---------------------------------------------------------------------------
__global__ __launch_bounds__(256) void proj_kv_kernel(
    const float* __restrict__ rs, const float* __restrict__ Wk,
    const float* __restrict__ Wv, unsigned short* __restrict__ k_ws,
    unsigned short* __restrict__ vt_ws) {
  __shared__ unsigned char smem[48 * 1024];
  unsigned char* rsh = smem;             // [64][128] f16 swz (16KB)
  unsigned char* wt = smem + 16 * 1024;  // [128][128] f16 swz, W^T (32KB)

  const int bid = blockIdx.x;
  const int b = bid >> 5;
  const int kt = bid & 31;
  const int m0 = kt << 6;
  const int tid = threadIdx.x;
  const int wv = tid >> 6, lane = tid & 63;

  {
    const float4* g = (const float4*)(rs + ((size_t)b * Mn + m0) * Cn);
#pragma unroll
    for (int i = 0; i < 8; ++i) {
      int f = tid + i * 256;
      int row = f >> 5, c4 = f & 31;
      float4 v = g[f];
      int byte = row * 256 + ((c4 * 8) ^ ((row & 7) << 4));
      *(ushort4*)(rsh + byte) =
          make_ushort4(f2h(v.x), f2h(v.y), f2h(v.z), f2h(v.w));
    }
  }

#define STAGE_WT(Wp)                                                          \
  {                                                                           \
    const float4* g = (const float4*)(Wp);                                    \
    _Pragma("unroll") for (int i = 0; i < 16; ++i) {                          \
      int f = tid + i * 256;                                                  \
      int c = f >> 5, d0 = (f & 31) * 4;                                      \
      float4 v = g[f];                                                        \
      float vv[4] = {v.x, v.y, v.z, v.w};                                     \
      _Pragma("unroll") for (int j = 0; j < 4; ++j) {                         \
        int row = d0 + j;                                                     \
        int byte = row * 256 + ((c * 2) ^ ((row & 7) << 4));                  \
        *(unsigned short*)(wt + byte) = f2h(vv[j]);                           \
      }                                                                       \
    }                                                                         \
  }

  STAGE_WT(Wk);
  __syncthreads();

  const int arow = wv * 16 + (lane & 15);
  f16x8 ah[4];
#pragma unroll
  for (int ks = 0; ks < 4; ++ks)
    ah[ks] = lds_read8(rsh, arow, 256, (lane >> 4) * 16 + ks * 64);

  f32x4 acc[8];
#pragma unroll
  for (int df = 0; df < 8; ++df) acc[df] = (f32x4)(0.0f);
#pragma unroll
  for (int ks = 0; ks < 4; ++ks)
#pragma unroll
    for (int df = 0; df < 8; ++df) {
      f16x8 bf = lds_read8(wt, df * 16 + (lane & 15), 256,
                           (lane >> 4) * 16 + ks * 64);
      acc[df] = __builtin_amdgcn_mfma_f32_16x16x32_f16(ah[ks], bf, acc[df], 0, 0, 0);
    }
  {
    // K tile: LINEAR row-major [m][d] f16
    unsigned char* kb = (unsigned char*)(k_ws + ((size_t)b * NTILES + kt) * 8192);
#pragma unroll
    for (int df = 0; df < 8; ++df)
#pragma unroll
      for (int r = 0; r < 4; ++r) {
        int row = wv * 16 + (lane >> 4) * 4 + r;   // tile-local m
        int dcol = df * 16 + (lane & 15);
        *(unsigned short*)(kb + row * 256 + dcol * 2) = f2h(acc[df][r]);
      }
  }
  __syncthreads();

  STAGE_WT(Wv);
  __syncthreads();
#pragma unroll
  for (int df = 0; df < 8; ++df) acc[df] = (f32x4)(0.0f);
#pragma unroll
  for (int ks = 0; ks < 4; ++ks)
#pragma unroll
    for (int df = 0; df < 8; ++df) {
      f16x8 bf = lds_read8(wt, df * 16 + (lane & 15), 256,
                           (lane >> 4) * 16 + ks * 64);
      acc[df] = __builtin_amdgcn_mfma_f32_16x16x32_f16(ah[ks], bf, acc[df], 0, 0, 0);
    }
  {
    unsigned char* vb = (unsigned char*)(vt_ws + ((size_t)b * NTILES + kt) * 8192);
#pragma unroll
    for (int df = 0; df < 8; ++df)
#pragma unroll
      for (int r = 0; r < 4; ++r) {
        int row = wv * 16 + (lane >> 4) * 4 + r;   // tile-local m
        int dcol = df * 16 + (lane & 15);          // d (row of V^T tile)
        int byte = dcol * 128 + ((row * 2) ^ ((dcol & 7) << 4));
        *(unsigned short*)(vb + byte) = f2h(acc[df][r]);
      }
  }
#undef STAGE_WT
}

// ---------------------------------------------------------------------------
// Kernel B: fused flash attention, transposed dataflow, K from L2.
// grid 512 blocks x 256 thr (4 waves x 32 q-rows). LDS 64KB:
//  prologue: xa[128][128]f16 @0 (32K), wq^T @32K (32K)
//  main: V0 @0 (16K), V1 @16K, P @32K + wv*4K
// XCD-chunked mapping: phys block p -> xcd = p&7 (hw rr); xcd pair (2b,2b+1)
// owns batch b -> per-XCD L2 working set = K+V of one batch (2MB).
// ---------------------------------------------------------------------------
__global__ __launch_bounds__(256, 2) void attn_kernel(
    const float* __restrict__ x, const float* __restrict__ Wq,
    const unsigned short* __restrict__ k_ws,
    const unsigned short* __restrict__ vt_ws, float* __restrict__ out) {
  __shared__ unsigned char smem[64 * 1024];

  const int bx = blockIdx.x;
  const int g8 = bx & 7;                 // -> XCD (hw round-robin)
  const int s = bx >> 3;                 // 0..63
  const int b = g8 >> 1;                 // batch per XCD-pair
  const int i = ((g8 & 1) << 6) | s;     // 0..127 within batch
  const int t = i >> 4;
  const int n0 = (i & 15) * QROWS;
  const int tid = threadIdx.x;
  const int wv = tid >> 6, lane = tid & 63;
  const int c = lane & 15, g = lane >> 4;

  const float* xg = x + (((size_t)b * Tn + t) * Nn + n0) * Cn;  // 128x128
  unsigned char* xa = smem;
  unsigned char* wqb = smem + 32 * 1024;
  unsigned char* pb = smem + 32 * 1024 + wv * 4096;  // main-loop P (per-wave)

  // ---- prologue: q = x@Wq (f16), scaled by log2(e), kept in regs ----
  {
    const float4* gp = (const float4*)xg;
#pragma unroll
    for (int ii = 0; ii < 16; ++ii) {
      int f = tid + ii * 256;
      int row = f >> 5, c4 = f & 31;
      float4 v = gp[f];
      int byte = row * 256 + ((c4 * 8) ^ ((row & 7) << 4));
      *(ushort4*)(xa + byte) =
          make_ushort4(f2h(v.x), f2h(v.y), f2h(v.z), f2h(v.w));
    }
  }
  {
    const float4* gp = (const float4*)Wq;
#pragma unroll
    for (int ii = 0; ii < 16; ++ii) {
      int f = tid + ii * 256;
      int cc = f >> 5, d0 = (f & 31) * 4;
      float4 v = gp[f];
      float vv[4] = {v.x, v.y, v.z, v.w};
#pragma unroll
      for (int j = 0; j < 4; ++j) {
        int row = d0 + j;
        int byte = row * 256 + ((cc * 2) ^ ((row & 7) << 4));
        *(unsigned short*)(wqb + byte) = f2h(vv[j]);
      }
    }
  }
  __syncthreads();

  f32x4 qacc[2][8];
#pragma unroll
  for (int rb = 0; rb < 2; ++rb)
#pragma unroll
    for (int df = 0; df < 8; ++df) qacc[rb][df] = (f32x4)(0.0f);
  {
    f16x8 xf[2][4];
#pragma unroll
    for (int rb = 0; rb < 2; ++rb)
#pragma unroll
      for (int ks = 0; ks < 4; ++ks)
        xf[rb][ks] = lds_read8(xa, wv * 32 + rb * 16 + c, 256, g * 16 + ks * 64);
#pragma unroll
    for (int ks = 0; ks < 4; ++ks)
#pragma unroll
      for (int df = 0; df < 8; ++df) {
        f16x8 bf = lds_read8(wqb, df * 16 + c, 256, g * 16 + ks * 64);
        qacc[0][df] = __builtin_amdgcn_mfma_f32_16x16x32_f16(xf[0][ks], bf, qacc[0][df], 0, 0, 0);
        qacc[1][df] = __builtin_amdgcn_mfma_f32_16x16x32_f16(xf[1][ks], bf, qacc[1][df], 0, 0, 0);
      }
  }
  // write q*log2e (f16) into own rows of xa, re-read as fragments (wave-local)
  const float LOG2E = 1.4426950408889634f;
#pragma unroll
  for (int rb = 0; rb < 2; ++rb)
#pragma unroll
    for (int df = 0; df < 8; ++df)
#pragma unroll
      for (int r = 0; r < 4; ++r) {
        int row = wv * 32 + rb * 16 + g * 4 + r;
        int col = df * 16 + c;
        int byte = row * 256 + ((col * 2) ^ ((row & 7) << 4));
        *(unsigned short*)(xa + byte) = f2h(qacc[rb][df][r] * LOG2E);
      }
  f16x8 qf[2][4];
#pragma unroll
  for (int rb = 0; rb < 2; ++rb)
#pragma unroll
    for (int ks = 0; ks < 4; ++ks)
      qf[rb][ks] = lds_read8(xa, wv * 32 + rb * 16 + c, 256, g * 16 + ks * 64);
  __syncthreads();

  // ---- main flash loop ----
  f32x4 o[2][8];  // O^T fragments: col c = q-row, rows = d
#pragma unroll
  for (int rb = 0; rb < 2; ++rb)
#pragma unroll
    for (int df = 0; df < 8; ++df) o[rb][df] = (f32x4)(0.0f);
  float mrow[2] = {-INFINITY, -INFINITY};
  float lrow[2] = {0.f, 0.f};  // per-lane partial (reduced at end)

  const unsigned char* khg = (const unsigned char*)(k_ws + (size_t)b * NTILES * 8192);
  const unsigned char* vtg = (const unsigned char*)(vt_ws + (size_t)b * NTILES * 8192);
  const int klane = c * 256 + g * 16;  // per-lane K A-frag base offset

  auto kload = [&](f16x8* kreg, int kt) {
    const unsigned char* kb = khg + (size_t)kt * 16384 + klane;
#pragma unroll
    for (int ks = 0; ks < 4; ++ks)
#pragma unroll
      for (int kvb = 0; kvb < 4; ++kvb)
        kreg[ks * 4 + kvb] = *(const f16x8*)(kb + kvb * 4096 + ks * 64);
  };
  auto stage = [&](unsigned char* buf, int kt) {
    const unsigned char* vt = vtg + (size_t)kt * 16384;
    int o16 = tid * 16;
#pragma unroll
    for (int h = 0; h < 4; ++h)
      gld16(vt + o16 + h * 4096, buf + o16 + h * 4096);
  };

  unsigned char* B0 = smem;
  unsigned char* B1 = smem + 16 * 1024;

  f16x8 kreg[16];
  stage(B0, 0);
  kload(kreg, 0);
  __syncthreads();

#pragma unroll 1
  for (int it = 0; it < NTILES; ++it) {
    unsigned char* curv = (it & 1) ? B1 : B0;
    unsigned char* altv = (it & 1) ? B0 : B1;

    // S^T[kv][q] = K @ Q (A=K from kreg, B=Q from regs)
    f32x4 st[2][4];
#pragma unroll
    for (int rb = 0; rb < 2; ++rb)
#pragma unroll
      for (int kvb = 0; kvb < 4; ++kvb) st[rb][kvb] = (f32x4)(0.0f);
    __builtin_amdgcn_s_setprio(1);
#pragma unroll
    for (int ks = 0; ks < 4; ++ks)
#pragma unroll
      for (int kvb = 0; kvb < 4; ++kvb) {
        f16x8 kf = kreg[ks * 4 + kvb];
        st[0][kvb] = __builtin_amdgcn_mfma_f32_16x16x32_f16(kf, qf[0][ks], st[0][kvb], 0, 0, 0);
        st[1][kvb] = __builtin_amdgcn_mfma_f32_16x16x32_f16(kf, qf[1][ks], st[1][kvb], 0, 0, 0);
      }
    __builtin_amdgcn_s_setprio(0);

    // prefetch next tile: K -> regs, V -> alternate LDS buffer
    if (it + 1 < NTILES) {
      kload(kreg, it + 1);
      stage(altv, it + 1);
    }

    // online softmax, log2 units; lane owns q-col c; defer-max (THR=8)
#pragma unroll
    for (int rb = 0; rb < 2; ++rb) {
      float tm = st[rb][0][0];
#pragma unroll
      for (int kvb = 0; kvb < 4; ++kvb)
#pragma unroll
        for (int r = 0; r < 4; ++r) tm = fmaxf(tm, st[rb][kvb][r]);
      tm = fmaxf(tm, __shfl_xor(tm, 16));
      tm = fmaxf(tm, __shfl_xor(tm, 32));
      float mn = mrow[rb];
      if (__any(tm > mn + 8.f)) {
        float newm = fmaxf(mn, tm);
        float scl = exp2f(mn - newm);
#pragma unroll
        for (int df = 0; df < 8; ++df) o[rb][df] *= scl;
        lrow[rb] *= scl;
        mrow[rb] = newm;
        mn = newm;
      }
      float ps = 0.f;
#pragma unroll
      for (int kvb = 0; kvb < 4; ++kvb) {
#pragma unroll
        for (int r = 0; r < 4; ++r) {
          float p = exp2f(st[rb][kvb][r] - mn);
          st[rb][kvb][r] = p;
          ps += p;
        }
        // packed P write: [q=c][kv] f16, swizzled, u32 pairs
#pragma unroll
        for (int h = 0; h < 2; ++h) {
          auto pk = __builtin_amdgcn_cvt_pkrtz(st[rb][kvb][2 * h],
                                               st[rb][kvb][2 * h + 1]);
          int kv2 = kvb * 32 + g * 8 + h * 4;  // kv*2 bytes
          int byte = c * 128 + (kv2 ^ ((c & 7) << 4));
          *(unsigned int*)(pb + rb * 2048 + byte) =
              __builtin_bit_cast(unsigned int, pk);
        }
      }
      lrow[rb] += ps;
    }

    // O^T += V^T @ P  (A = V^T rows d from LDS, B = P from per-wave LDS)
    f16x8 pa[2][2];
#pragma unroll
    for (int rb = 0; rb < 2; ++rb)
#pragma unroll
      for (int ks = 0; ks < 2; ++ks)
        pa[rb][ks] = lds_read8(pb + rb * 2048, c, 128, g * 16 + ks * 64);
    __builtin_amdgcn_s_setprio(1);
#pragma unroll
    for (int ks = 0; ks < 2; ++ks)
#pragma unroll
      for (int df = 0; df < 8; ++df) {
        f16x8 vf = lds_read8(curv, df * 16 + c, 128, g * 16 + ks * 64);
        o[0][df] = __builtin_amdgcn_mfma_f32_16x16x32_f16(vf, pa[0][ks], o[0][df], 0, 0, 0);
        o[1][df] = __builtin_amdgcn_mfma_f32_16x16x32_f16(vf, pa[1][ks], o[1][df], 0, 0, 0);
      }
    __builtin_amdgcn_s_setprio(0);
    __syncthreads();
  }

  // ---- epilogue: reduce l across groups, out = x + O/l ----
#pragma unroll
  for (int rb = 0; rb < 2; ++rb) {
    lrow[rb] += __shfl_xor(lrow[rb], 16);
    lrow[rb] += __shfl_xor(lrow[rb], 32);
  }
  float inv[2] = {1.0f / lrow[0], 1.0f / lrow[1]};
#pragma unroll
  for (int rb = 0; rb < 2; ++rb)
#pragma unroll
    for (int df = 0; df < 8; ++df)
#pragma unroll
      for (int r = 0; r < 4; ++r) {
        int row = wv * 32 + rb * 16 + c;         // q-row (block-local)
        int d = df * 16 + g * 4 + r;
        int byte = row * 512 + ((d * 4) ^ ((row & 7) << 4));
        *(float*)(smem + byte) = o[rb][df][r] * inv[rb];
      }
  __syncthreads();
  {
    const float4* xg4 = (const float4*)xg;
    float4* og4 = (float4*)(out + (((size_t)b * Tn + t) * Nn + n0) * Cn);
#pragma unroll
    for (int ii = 0; ii < 16; ++ii) {
      int f = tid + ii * 256;
      int row = f >> 5, c4 = f & 31;
      int byte = row * 512 + ((c4 * 16) ^ ((row & 7) << 4));
      f32x4 v = *(const f32x4*)(smem + byte);
      float4 xv = xg4[f];
      og4[f] = make_float4(xv.x + v[0], xv.y + v[1], xv.z + v[2], xv.w + v[3]);
    }
  }
}

extern "C" void kernel_launch(void* const* d_in, const int* in_sizes, int n_in,
                              void* d_out, int out_size, void* d_ws,
                              size_t ws_size, hipStream_t stream) {
  const float* x = (const float*)d_in[0];
  const float* rs = (const float*)d_in[1];
  const float* Wq = (const float*)d_in[2];
  const float* Wk = (const float*)d_in[3];
  const float* Wv = (const float*)d_in[4];
  float* out = (float*)d_out;

  // ws: K f16 tiles [B][32][8192] (2MB, linear) | V^T f16 tiles (2MB, swz)
  unsigned short* k_ws = (unsigned short*)d_ws;
  unsigned short* vt_ws = k_ws + (size_t)Bn * Mn * Cn;

  proj_kv_kernel<<<Bn * NTILES, 256, 0, stream>>>(rs, Wk, Wv, k_ws, vt_ws);
  attn_kernel<<<Bn * Tn * NQT, 256, 0, stream>>>(x, Wq, k_ws, vt_ws, out);
}

// Round 7
// 134.603 us; speedup vs baseline: 1.3330x; 1.3330x over previous
//
#include <hip/hip_runtime.h>

// out = x + softmax((x@Wq) @ (rs@Wk)^T) @ (rs@Wv)
// B=4 T=8 N=2048 C=D=128 M=2048. fp32 in/out, fp16 MFMA compute (f32 accum).
// R6: software-pipelined flash loop: [QK^T(t) | PV(t-1)] MFMA cluster,
//     raw s_barrier + counted vmcnt (loads stay in flight across barrier),
//     KVBLK=32, K 2-buf / V 4-buf, vote-only defer-max, f16 O epilogue.

#define Bn 4
#define Tn 8
#define Nn 2048
#define Cn 128
#define Mn 2048
#define KVB 32
#define NT 64            // Mn/KVB
#define QROWS 128
#define NQT (Nn / QROWS) // 16

typedef __attribute__((ext_vector_type(4))) float f32x4;
typedef __attribute__((ext_vector_type(8))) _Float16 f16x8;
typedef __attribute__((address_space(3))) unsigned char lds_uc;
typedef const __attribute__((address_space(1))) unsigned char glb_uc;

__device__ __forceinline__ unsigned short f2h(float f) {
  _Float16 h = (_Float16)f;
  return __builtin_bit_cast(unsigned short, h);
}
__device__ __forceinline__ unsigned int pk2(float a, float b) {
  auto v = __builtin_amdgcn_cvt_pkrtz(a, b);
  return __builtin_bit_cast(unsigned int, v);
}
// 16B LDS read, 256B rows, swizzle (row&7)<<4
__device__ __forceinline__ f16x8 lds_read8(const unsigned char* base, int row,
                                           int colByte) {
  int byte = row * 256 + (colByte ^ ((row & 7) << 4));
  return *(const f16x8*)(base + byte);
}
// 16B LDS read, 64B rows, swizzle (row&3)<<4
__device__ __forceinline__ f16x8 lds_read8v(const unsigned char* base, int row,
                                            int colByte) {
  int byte = row * 64 + (colByte ^ ((row & 3) << 4));
  return *(const f16x8*)(base + byte);
}
__device__ __forceinline__ void gld16(const void* g, void* l) {
  __builtin_amdgcn_global_load_lds((glb_uc*)g, (lds_uc*)l, 16, 0, 0);
}

// ---------------------------------------------------------------------------
// Kernel A: K tiles [B][NT][32 m][128 d] f16 pre-swizzled ((row&7)<<4, 256B
// rows); V^T tiles [B][NT][128 d][32 m] f16 pre-swizzled ((d&3)<<4, 64B rows).
// grid: B*32 = 128 blocks (each does 64 m-rows = 2 kv-tiles), 256 threads.
// ---------------------------------------------------------------------------
__global__ __launch_bounds__(256) void proj_kv_kernel(
    const float* __restrict__ rs, const float* __restrict__ Wk,
    const float* __restrict__ Wv, unsigned short* __restrict__ k_ws,
    unsigned short* __restrict__ vt_ws) {
  __shared__ unsigned char smem[48 * 1024];
  unsigned char* rsh = smem;             // [64][128] f16 swz (16KB)
  unsigned char* wt = smem + 16 * 1024;  // [128][128] f16 swz, W^T (32KB)

  const int bid = blockIdx.x;
  const int b = bid >> 5;
  const int kt64 = bid & 31;
  const int m0 = kt64 << 6;
  const int tid = threadIdx.x;
  const int wv = tid >> 6, lane = tid & 63;

  {
    const float4* g = (const float4*)(rs + ((size_t)b * Mn + m0) * Cn);
#pragma unroll
    for (int i = 0; i < 8; ++i) {
      int f = tid + i * 256;
      int row = f >> 5, c4 = f & 31;
      float4 v = g[f];
      int byte = row * 256 + ((c4 * 8) ^ ((row & 7) << 4));
      *(ushort4*)(rsh + byte) =
          make_ushort4(f2h(v.x), f2h(v.y), f2h(v.z), f2h(v.w));
    }
  }

#define STAGE_WT(Wp)                                                          \
  {                                                                           \
    const float4* g = (const float4*)(Wp);                                    \
    _Pragma("unroll") for (int i = 0; i < 16; ++i) {                          \
      int f = tid + i * 256;                                                  \
      int cc = f >> 5, d0 = (f & 31) * 4;                                     \
      float4 v = g[f];                                                        \
      float vv[4] = {v.x, v.y, v.z, v.w};                                     \
      _Pragma("unroll") for (int j = 0; j < 4; ++j) {                         \
        int row = d0 + j;                                                     \
        int byte = row * 256 + ((cc * 2) ^ ((row & 7) << 4));                 \
        *(unsigned short*)(wt + byte) = f2h(vv[j]);                           \
      }                                                                       \
    }                                                                         \
  }

  STAGE_WT(Wk);
  __syncthreads();

  const int arow = wv * 16 + (lane & 15);
  f16x8 ah[4];
#pragma unroll
  for (int ks = 0; ks < 4; ++ks)
    ah[ks] = lds_read8(rsh, arow, (lane >> 4) * 16 + ks * 64);

  f32x4 acc[8];
#pragma unroll
  for (int df = 0; df < 8; ++df) acc[df] = (f32x4)(0.0f);
#pragma unroll
  for (int ks = 0; ks < 4; ++ks)
#pragma unroll
    for (int df = 0; df < 8; ++df) {
      f16x8 bf = lds_read8(wt, df * 16 + (lane & 15), (lane >> 4) * 16 + ks * 64);
      acc[df] = __builtin_amdgcn_mfma_f32_16x16x32_f16(ah[ks], bf, acc[df], 0, 0, 0);
    }
  {
    unsigned char* kb = (unsigned char*)k_ws;
#pragma unroll
    for (int df = 0; df < 8; ++df)
#pragma unroll
      for (int r = 0; r < 4; ++r) {
        int row = wv * 16 + (lane >> 4) * 4 + r;   // 0..63 block-local m
        int dcol = df * 16 + (lane & 15);
        size_t tile = (size_t)b * NT + (m0 >> 5) + (row >> 5);
        size_t byte = tile * 8192 + (row & 31) * 256 +
                      ((dcol * 2) ^ ((row & 7) << 4));
        *(unsigned short*)(kb + byte) = f2h(acc[df][r]);
      }
  }
  __syncthreads();

  STAGE_WT(Wv);
  __syncthreads();
#pragma unroll
  for (int df = 0; df < 8; ++df) acc[df] = (f32x4)(0.0f);
#pragma unroll
  for (int ks = 0; ks < 4; ++ks)
#pragma unroll
    for (int df = 0; df < 8; ++df) {
      f16x8 bf = lds_read8(wt, df * 16 + (lane & 15), (lane >> 4) * 16 + ks * 64);
      acc[df] = __builtin_amdgcn_mfma_f32_16x16x32_f16(ah[ks], bf, acc[df], 0, 0, 0);
    }
  {
    unsigned char* vb = (unsigned char*)vt_ws;
#pragma unroll
    for (int df = 0; df < 8; ++df)
#pragma unroll
      for (int r = 0; r < 4; ++r) {
        int row = wv * 16 + (lane >> 4) * 4 + r;   // block-local m
        int dcol = df * 16 + (lane & 15);          // d
        size_t tile = (size_t)b * NT + (m0 >> 5) + (row >> 5);
        size_t byte = tile * 8192 + dcol * 64 +
                      (((row & 31) * 2) ^ ((dcol & 3) << 4));
        *(unsigned short*)(vb + byte) = f2h(acc[df][r]);
      }
  }
#undef STAGE_WT
}

// ---------------------------------------------------------------------------
// Kernel B: pipelined flash attention. grid 512 x 256 thr (4 waves x 32 q).
// LDS 64KB: prologue {xa 32K @0, wq^T 32K @32K};
// main: K[2] 8K @0, V[4] 8K @16K, P @48K + wv*2K; epilogue O bounce 32K @0.
// Per iter: QK^T(t) + PV(t-1) MFMA cluster; stage K(t+1),V(t+2); softmax(t);
// counted vmcnt + raw s_barrier (DMA stays in flight across barrier).
// ---------------------------------------------------------------------------
__global__ __launch_bounds__(256, 2) void attn_kernel(
    const float* __restrict__ x, const float* __restrict__ Wq,
    const unsigned short* __restrict__ k_ws,
    const unsigned short* __restrict__ vt_ws, float* __restrict__ out) {
  __shared__ unsigned char smem[64 * 1024];

  const int bx = blockIdx.x;
  const int wb = ((bx & 7) << 6) | (bx >> 3);  // XCD swizzle (512 % 8 == 0)
  const int b = wb >> 7;
  const int t_ = (wb >> 4) & 7;
  const int n0 = (wb & 15) * QROWS;
  const int tid = threadIdx.x;
  const int wv = tid >> 6, lane = tid & 63;
  const int c = lane & 15, g = lane >> 4;

  const float* xg = x + (((size_t)b * Tn + t_) * Nn + n0) * Cn;  // 128x128
  unsigned char* xa = smem;
  unsigned char* wqb = smem + 32 * 1024;
  unsigned char* pb = smem + 48 * 1024 + wv * 2048;

  // ---- prologue: q = x@Wq (f16) * log2e, kept as B-fragments in regs ----
  {
    const float4* gp = (const float4*)xg;
#pragma unroll
    for (int ii = 0; ii < 16; ++ii) {
      int f = tid + ii * 256;
      int row = f >> 5, c4 = f & 31;
      float4 v = gp[f];
      int byte = row * 256 + ((c4 * 8) ^ ((row & 7) << 4));
      *(ushort4*)(xa + byte) =
          make_ushort4(f2h(v.x), f2h(v.y), f2h(v.z), f2h(v.w));
    }
  }
  {
    const float4* gp = (const float4*)Wq;
#pragma unroll
    for (int ii = 0; ii < 16; ++ii) {
      int f = tid + ii * 256;
      int cc = f >> 5, d0 = (f & 31) * 4;
      float4 v = gp[f];
      float vv[4] = {v.x, v.y, v.z, v.w};
#pragma unroll
      for (int j = 0; j < 4; ++j) {
        int row = d0 + j;
        int byte = row * 256 + ((cc * 2) ^ ((row & 7) << 4));
        *(unsigned short*)(wqb + byte) = f2h(vv[j]);
      }
    }
  }
  __syncthreads();

  f32x4 qacc[2][8];
#pragma unroll
  for (int rb = 0; rb < 2; ++rb)
#pragma unroll
    for (int df = 0; df < 8; ++df) qacc[rb][df] = (f32x4)(0.0f);
  {
    f16x8 xf[2][4];
#pragma unroll
    for (int rb = 0; rb < 2; ++rb)
#pragma unroll
      for (int ks = 0; ks < 4; ++ks)
        xf[rb][ks] = lds_read8(xa, wv * 32 + rb * 16 + c, g * 16 + ks * 64);
#pragma unroll
    for (int ks = 0; ks < 4; ++ks)
#pragma unroll
      for (int df = 0; df < 8; ++df) {
        f16x8 bf = lds_read8(wqb, df * 16 + c, g * 16 + ks * 64);
        qacc[0][df] = __builtin_amdgcn_mfma_f32_16x16x32_f16(xf[0][ks], bf, qacc[0][df], 0, 0, 0);
        qacc[1][df] = __builtin_amdgcn_mfma_f32_16x16x32_f16(xf[1][ks], bf, qacc[1][df], 0, 0, 0);
      }
  }
  const float LOG2E = 1.4426950408889634f;
#pragma unroll
  for (int rb = 0; rb < 2; ++rb)
#pragma unroll
    for (int df = 0; df < 8; ++df)
#pragma unroll
      for (int r = 0; r < 4; ++r) {
        int row = wv * 32 + rb * 16 + g * 4 + r;
        int col = df * 16 + c;
        int byte = row * 256 + ((col * 2) ^ ((row & 7) << 4));
        *(unsigned short*)(xa + byte) = f2h(qacc[rb][df][r] * LOG2E);
      }
  f16x8 qf[2][4];
#pragma unroll
  for (int rb = 0; rb < 2; ++rb)
#pragma unroll
    for (int ks = 0; ks < 4; ++ks)
      qf[rb][ks] = lds_read8(xa, wv * 32 + rb * 16 + c, g * 16 + ks * 64);
  __syncthreads();  // prologue LDS dead; main buffers take over

  // ---- main pipelined flash loop ----
  f32x4 o[2][8];
#pragma unroll
  for (int rb = 0; rb < 2; ++rb)
#pragma unroll
    for (int df = 0; df < 8; ++df) o[rb][df] = (f32x4)(0.0f);
  float mrow[2] = {-INFINITY, -INFINITY};
  float lrow[2] = {0.f, 0.f};

  const unsigned char* khg = (const unsigned char*)k_ws + (size_t)b * NT * 8192;
  const unsigned char* vtg = (const unsigned char*)vt_ws + (size_t)b * NT * 8192;

  auto stageK = [&](int t) {
    const unsigned char* s = khg + (size_t)t * 8192 + tid * 16;
    unsigned char* d = smem + (t & 1) * 8192 + tid * 16;
    gld16(s, d);
    gld16(s + 4096, d + 4096);
  };
  auto stageV = [&](int t) {
    const unsigned char* s = vtg + (size_t)t * 8192 + tid * 16;
    unsigned char* d = smem + 16 * 1024 + (t & 3) * 8192 + tid * 16;
    gld16(s, d);
    gld16(s + 4096, d + 4096);
  };

  stageK(0);
  stageV(0);
  stageV(1);
  asm volatile("s_waitcnt vmcnt(2)" ::: "memory");  // K0,V0 landed; V1 in flight
  __builtin_amdgcn_s_barrier();

  f16x8 pa[2];  // P fragments carried across iterations
#pragma unroll 1
  for (int t = 0; t < NT; ++t) {
    unsigned char* kb = smem + (t & 1) * 8192;
    unsigned char* vbp = smem + 16 * 1024 + ((t - 1) & 3) * 8192;

    // 1+2. MFMA cluster: QK^T(t) then PV(t-1)
    f32x4 st[2][2];
#pragma unroll
    for (int rb = 0; rb < 2; ++rb)
#pragma unroll
      for (int kvb = 0; kvb < 2; ++kvb) st[rb][kvb] = (f32x4)(0.0f);
    __builtin_amdgcn_s_setprio(1);
#pragma unroll
    for (int ks = 0; ks < 4; ++ks)
#pragma unroll
      for (int kvb = 0; kvb < 2; ++kvb) {
        f16x8 kf = lds_read8(kb, kvb * 16 + c, g * 16 + ks * 64);
        st[0][kvb] = __builtin_amdgcn_mfma_f32_16x16x32_f16(kf, qf[0][ks], st[0][kvb], 0, 0, 0);
        st[1][kvb] = __builtin_amdgcn_mfma_f32_16x16x32_f16(kf, qf[1][ks], st[1][kvb], 0, 0, 0);
      }
    if (t > 0) {
#pragma unroll
      for (int df = 0; df < 8; ++df) {
        f16x8 vf = lds_read8v(vbp, df * 16 + c, g * 16);
        o[0][df] = __builtin_amdgcn_mfma_f32_16x16x32_f16(vf, pa[0], o[0][df], 0, 0, 0);
        o[1][df] = __builtin_amdgcn_mfma_f32_16x16x32_f16(vf, pa[1], o[1][df], 0, 0, 0);
      }
    }
    __builtin_amdgcn_s_setprio(0);

    // 3. stage next tiles (stay in flight across the barrier)
    if (t + 1 < NT) stageK(t + 1);
    if (t + 2 < NT) stageV(t + 2);

    // 4. softmax(t): vote-only defer-max (log2 units), pack P to LDS
#pragma unroll
    for (int rb = 0; rb < 2; ++rb) {
      float tm = st[rb][0][0];
#pragma unroll
      for (int kvb = 0; kvb < 2; ++kvb)
#pragma unroll
        for (int r = 0; r < 4; ++r) tm = fmaxf(tm, st[rb][kvb][r]);
      if (__any(tm > mrow[rb] + 8.f)) {  // rare path
        tm = fmaxf(tm, __shfl_xor(tm, 16));
        tm = fmaxf(tm, __shfl_xor(tm, 32));
        float newm = fmaxf(mrow[rb], tm);
        float scl = exp2f(mrow[rb] - newm);
#pragma unroll
        for (int df = 0; df < 8; ++df) o[rb][df] *= scl;
        lrow[rb] *= scl;
        mrow[rb] = newm;
      }
      float mn = mrow[rb];
      float ps = 0.f;
#pragma unroll
      for (int kvb = 0; kvb < 2; ++kvb) {
        float p0 = exp2f(st[rb][kvb][0] - mn);
        float p1 = exp2f(st[rb][kvb][1] - mn);
        float p2 = exp2f(st[rb][kvb][2] - mn);
        float p3 = exp2f(st[rb][kvb][3] - mn);
        ps += (p0 + p1) + (p2 + p3);
        int kv2 = kvb * 32 + g * 8;  // kv*2 bytes
        int base = rb * 1024 + c * 64;
        int swz = (c & 3) << 4;
        *(unsigned int*)(pb + base + (kv2 ^ swz)) = pk2(p0, p1);
        *(unsigned int*)(pb + base + ((kv2 + 4) ^ swz)) = pk2(p2, p3);
      }
      lrow[rb] += ps;
    }

    // 5. P fragments for PV(t) (in-wave DS write->read ordering)
    pa[0] = lds_read8v(pb, c, g * 16);
    pa[1] = lds_read8v(pb + 1024, c, g * 16);

    // 6. counted drain + raw barrier
    if (t < NT - 1) {
      if (t < NT - 2)
        asm volatile("s_waitcnt vmcnt(2)" ::: "memory");  // V(t+2) in flight
      else
        asm volatile("s_waitcnt vmcnt(0)" ::: "memory");
      __builtin_amdgcn_s_barrier();
    }
  }
  // tail: PV(NT-1)
  {
    unsigned char* vbp = smem + 16 * 1024 + ((NT - 1) & 3) * 8192;
#pragma unroll
    for (int df = 0; df < 8; ++df) {
      f16x8 vf = lds_read8v(vbp, df * 16 + c, g * 16);
      o[0][df] = __builtin_amdgcn_mfma_f32_16x16x32_f16(vf, pa[0], o[0][df], 0, 0, 0);
      o[1][df] = __builtin_amdgcn_mfma_f32_16x16x32_f16(vf, pa[1], o[1][df], 0, 0, 0);
    }
  }
  __syncthreads();

  // ---- epilogue: l-reduce, O (f16-packed) bounce, out = x + O/l ----
#pragma unroll
  for (int rb = 0; rb < 2; ++rb) {
    lrow[rb] += __shfl_xor(lrow[rb], 16);
    lrow[rb] += __shfl_xor(lrow[rb], 32);
  }
  float inv[2] = {1.0f / lrow[0], 1.0f / lrow[1]};
#pragma unroll
  for (int rb = 0; rb < 2; ++rb)
#pragma unroll
    for (int df = 0; df < 8; ++df)
#pragma unroll
      for (int tq = 0; tq < 2; ++tq) {
        int d0 = df * 16 + g * 4 + tq * 2;
        int row = wv * 32 + rb * 16 + c;
        int byte = row * 256 + ((d0 * 2) ^ ((row & 7) << 4));
        *(unsigned int*)(smem + byte) =
            pk2(o[rb][df][2 * tq] * inv[rb], o[rb][df][2 * tq + 1] * inv[rb]);
      }
  __syncthreads();
  {
    const float4* xg4 = (const float4*)xg;
    float4* og4 = (float4*)(out + (((size_t)b * Tn + t_) * Nn + n0) * Cn);
#pragma unroll
    for (int ii = 0; ii < 8; ++ii) {
      int f = tid + ii * 256;
      int row = f >> 4, c16 = f & 15;
      int byte = row * 256 + ((c16 * 16) ^ ((row & 7) << 4));
      f16x8 v = *(const f16x8*)(smem + byte);
      float4 x0 = xg4[row * 32 + c16 * 2];
      float4 x1 = xg4[row * 32 + c16 * 2 + 1];
      og4[row * 32 + c16 * 2] =
          make_float4(x0.x + (float)v[0], x0.y + (float)v[1],
                      x0.z + (float)v[2], x0.w + (float)v[3]);
      og4[row * 32 + c16 * 2 + 1] =
          make_float4(x1.x + (float)v[4], x1.y + (float)v[5],
                      x1.z + (float)v[6], x1.w + (float)v[7]);
    }
  }
}

extern "C" void kernel_launch(void* const* d_in, const int* in_sizes, int n_in,
                              void* d_out, int out_size, void* d_ws,
                              size_t ws_size, hipStream_t stream) {
  const float* x = (const float*)d_in[0];
  const float* rs = (const float*)d_in[1];
  const float* Wq = (const float*)d_in[2];
  const float* Wk = (const float*)d_in[3];
  const float* Wv = (const float*)d_in[4];
  float* out = (float*)d_out;

  // ws: K f16 tiles [B][64][4096] (2MB, pre-swz) | V^T tiles (2MB, pre-swz)
  unsigned short* k_ws = (unsigned short*)d_ws;
  unsigned short* vt_ws = k_ws + (size_t)Bn * Mn * Cn;

  proj_kv_kernel<<<Bn * 32, 256, 0, stream>>>(rs, Wk, Wv, k_ws, vt_ws);
  attn_kernel<<<Bn * Tn * NQT, 256, 0, stream>>>(x, Wq, k_ws, vt_ws, out);
}